// Round 5
// baseline (86.617 us; speedup 1.0000x reference)
//
#include <hip/hip_runtime.h>
#include <math.h>

// Problem constants (B=8, N=2048, F=64, O=64), f32 in/out.
#define BB 8
#define NN 2048
#define FF 64
#define OO 64
#define KC 128                 // K-chunk per iteration
#define NITER (NN / KC)        // 16
constexpr float ALPHA = 0.2f;

typedef float  f32x4  __attribute__((ext_vector_type(4)));
typedef short  s16x8  __attribute__((ext_vector_type(8)));

// round-to-nearest-even f32 -> bf16, two packed into a u32
static __device__ __forceinline__ unsigned int packbf2(float a, float b) {
    unsigned int ua = __builtin_bit_cast(unsigned int, a);
    unsigned int ub = __builtin_bit_cast(unsigned int, b);
    ua = (ua + 0x7FFFu + ((ua >> 16) & 1u)) >> 16;
    ub = (ub + 0x7FFFu + ((ub >> 16) & 1u)) & 0xFFFF0000u;
    return ua | ub;
}

// ---------------------------------------------------------------------------
// K1: dInv[row] = 1/sqrt(1 + sum_m A[row,m]).  One block per row.
// ---------------------------------------------------------------------------
__global__ __launch_bounds__(256) void k_rowsum(const float* __restrict__ A,
                                                float* __restrict__ dInv) {
    const int row = blockIdx.x;
    const float* a = A + (size_t)row * NN;
    const int t = threadIdx.x;

    float4 v0 = *(const float4*)(a + t * 4);
    float4 v1 = *(const float4*)(a + t * 4 + 1024);
    float s = v0.x + v0.y + v0.z + v0.w + v1.x + v1.y + v1.z + v1.w;

    #pragma unroll
    for (int off = 32; off > 0; off >>= 1) s += __shfl_down(s, off, 64);

    __shared__ float partial[4];
    const int lane = t & 63, w = t >> 6;
    if (lane == 0) partial[w] = s;
    __syncthreads();
    if (t == 0) {
        float tot = partial[0] + partial[1] + partial[2] + partial[3] + 1.0f;
        dInv[row] = 1.0f / sqrtf(tot);
    }
}

// ---------------------------------------------------------------------------
// K2: Y[row,o] = dInv[row] * sum_f X[row,f] * W[f,o]
//     Yf  [b][n][o] f32  (self-term for epilogue)
//     Ytb [b][o][m] bf16 (transposed; k_main B-operand, L2-resident 256KB/batch)
// ---------------------------------------------------------------------------
__global__ __launch_bounds__(256) void k_xw(const float* __restrict__ X,
                                            const float* __restrict__ W,
                                            const float* __restrict__ dInv,
                                            float* __restrict__ Yf,
                                            ushort* __restrict__ Ytb) {
    __shared__ float Ws[FF][OO];
    __shared__ float Xs[16][FF];
    const int t = threadIdx.x;
    const int r0 = blockIdx.x * 16;

    #pragma unroll
    for (int j = 0; j < 4; ++j) {
        int f4 = t + 256 * j;
        ((float4*)Ws)[f4] = ((const float4*)W)[f4];
    }
    ((float4*)Xs)[t] = ((const float4*)(X + (size_t)r0 * FF))[t];
    __syncthreads();

    const int c = t & 63, g = t >> 6;
    float acc[4] = {0.f, 0.f, 0.f, 0.f};
    for (int f = 0; f < FF; ++f) {
        float wv = Ws[f][c];
        #pragma unroll
        for (int i = 0; i < 4; ++i) acc[i] += Xs[g * 4 + i][f] * wv;
    }
    float y[4];
    #pragma unroll
    for (int i = 0; i < 4; ++i) {
        int row = r0 + g * 4 + i;
        y[i] = dInv[row] * acc[i];
        Yf[(size_t)row * OO + c] = y[i];
    }
    const int b = r0 >> 11;
    const int n = (r0 & (NN - 1)) + g * 4;
    unsigned int p0 = packbf2(y[0], y[1]);
    unsigned int p1 = packbf2(y[2], y[3]);
    *(uint2*)(Ytb + ((size_t)b * OO + c) * NN + n) = make_uint2(p0, p1);
}

// ---------------------------------------------------------------------------
// K3 (MFMA): out0[b,n,o] = leaky( dInv[n]*(sum_m A[n,m]*Y[m,o] + Y[n,o]) + bias[o] )
//            outA = copy of A (fused with A staging loads).
// 1024 blocks (16 rows x 64 cols) x 256 thr (4 waves) -> 4 blocks/CU.
// Data layout identical to R4 (refcheck-verified). Sync structure relaxed:
//   - raw s_barrier, LDS visibility via lgkmcnt(0) only (+ sched_barrier)
//   - global A-copy stores are issued AFTER the next-tile loads, so the
//     compiler's wait-for-loads (in-order vmcnt) never drains the stores ->
//     stores stream across iterations instead of stalling each barrier.
// ---------------------------------------------------------------------------
__global__ __launch_bounds__(256, 4) void k_main(const float* __restrict__ A,
                                                 const ushort* __restrict__ Ytb,
                                                 const float* __restrict__ Yf,
                                                 const float* __restrict__ dInv,
                                                 const float* __restrict__ bias,
                                                 float* __restrict__ out0,
                                                 float* __restrict__ outA) {
    __shared__ ushort As[16][136];     // 4.25 KB
    __shared__ ushort Ys[64 * 128];    // 16 KB, [o][128], XOR-swizzled

    const int bx = blockIdx.x;          // 1024
    const int b  = bx >> 7;
    const int n0 = (bx & 127) * 16;

    const float*  Ab   = A    + ((size_t)b * NN + n0) * NN;
    float*        Cb   = outA + ((size_t)b * NN + n0) * NN;
    const ushort* yb   = Ytb  + (size_t)b * OO * NN;
    const float*  Yf_b = Yf   + (size_t)b * NN * OO;
    float*        O_b  = out0 + (size_t)b * NN * OO;

    const int t = threadIdx.x;
    const int lane = t & 63, w = t >> 6;
    const int fr = lane & 15, fg = lane >> 4;

    // A staging coords (2 float4/thread)
    const int ar0 = t >> 5,         ac0 = (t & 31) * 4;
    const int ar1 = (t + 256) >> 5, ac1 = (t & 31) * 4;
    const float* aSrc0 = Ab + (size_t)ar0 * NN + ac0;
    const float* aSrc1 = Ab + (size_t)ar1 * NN + ac1;
    float*       aDst0 = Cb + (size_t)ar0 * NN + ac0;
    float*       aDst1 = Cb + (size_t)ar1 * NN + ac1;

    // Y staging coords (4 uint4/thread)
    const int yrBase = w * 16 + (lane >> 4);
    const int ycu    = (lane & 15) * 8;

    // fragment read bases
    const ushort* aFragBase = &As[fr][fg * 8];
    const int yRow = w * 16 + fr;
    const int ySwz = (fr & 7) << 3;

    f32x4 acc = {0.f, 0.f, 0.f, 0.f};

    float4 pa0, pa1;
    uint4  py0, py1, py2, py3;

    // prologue: prefetch tile 0
    pa0 = *(const float4*)(aSrc0);
    pa1 = *(const float4*)(aSrc1);
    {
        const ushort* s = yb + (size_t)yrBase * NN + ycu;
        py0 = *(const uint4*)(s);
        py1 = *(const uint4*)(s + 4 * NN);
        py2 = *(const uint4*)(s + 8 * NN);
        py3 = *(const uint4*)(s + 12 * NN);
    }

    for (int i = 0; i < NITER; ++i) {
        const int k0 = i * KC;

        // barrier A: all waves done reading LDS from the previous iteration.
        __builtin_amdgcn_s_barrier();

        // ---- LDS fill (from held regs; compiler waits vmcnt for these
        //      loads only — stores queued after them stay outstanding) ----
        {
            uint2 qa;
            qa.x = packbf2(pa0.x, pa0.y);
            qa.y = packbf2(pa0.z, pa0.w);
            *(uint2*)&As[ar0][ac0] = qa;
            qa.x = packbf2(pa1.x, pa1.y);
            qa.y = packbf2(pa1.z, pa1.w);
            *(uint2*)&As[ar1][ac1] = qa;
        }
        {
            const int r0w = yrBase;
            *(uint4*)&Ys[(r0w + 0) * 128 + (ycu ^ (((r0w + 0) & 7) << 3))] = py0;
            *(uint4*)&Ys[(r0w + 4) * 128 + (ycu ^ (((r0w + 4) & 7) << 3))] = py1;
            *(uint4*)&Ys[(r0w + 8) * 128 + (ycu ^ (((r0w + 8) & 7) << 3))] = py2;
            *(uint4*)&Ys[(r0w + 12) * 128 + (ycu ^ (((r0w + 12) & 7) << 3))] = py3;
        }

        // LDS visibility: commit ds_writes, then barrier B. No vmcnt drain.
        asm volatile("s_waitcnt lgkmcnt(0)" ::: "memory");
        __builtin_amdgcn_sched_barrier(0);
        __builtin_amdgcn_s_barrier();

        // ---- issue next-tile loads FIRST ... ----
        float4 npa0, npa1;
        uint4  npy0, npy1, npy2, npy3;
        if (i + 1 < NITER) {
            const int kn = k0 + KC;
            npa0 = *(const float4*)(aSrc0 + kn);
            npa1 = *(const float4*)(aSrc1 + kn);
            const ushort* s = yb + (size_t)yrBase * NN + kn + ycu;
            npy0 = *(const uint4*)(s);
            npy1 = *(const uint4*)(s + 4 * NN);
            npy2 = *(const uint4*)(s + 8 * NN);
            npy3 = *(const uint4*)(s + 12 * NN);
        }
        // ---- ... THEN the A copy-out stores (old regs) — they trail the
        //      loads in the in-order vmcnt queue, so no wait ever drains them.
        *(float4*)(aDst0 + k0) = pa0;
        *(float4*)(aDst1 + k0) = pa1;

        // ---- MFMA phase: 4 K-substeps of 32 ----
        #pragma unroll
        for (int ks = 0; ks < 4; ++ks) {
            s16x8 af = *(const s16x8*)(aFragBase + ks * 32);
            s16x8 bf = *(const s16x8*)&Ys[yRow * 128 + ((ks * 32 + fg * 8) ^ ySwz)];
            acc = __builtin_amdgcn_mfma_f32_16x16x32_bf16(af, bf, acc, 0, 0, 0);
        }

        pa0 = npa0; pa1 = npa1;
        py0 = npy0; py1 = npy1; py2 = npy2; py3 = npy3;
    }

    // ---- epilogue: D map col = lane&15, row = (lane>>4)*4 + reg ----
    const int col = w * 16 + fr;
    const float bv = bias[col];
    #pragma unroll
    for (int r = 0; r < 4; ++r) {
        const int nrow = n0 + fg * 4 + r;
        const float di = dInv[(size_t)b * NN + nrow];
        float v = di * (acc[r] + Yf_b[(size_t)nrow * OO + col]) + bv;
        O_b[(size_t)nrow * OO + col] = (v >= 0.f) ? v : ALPHA * v;
    }
}

// ---------------------------------------------------------------------------
extern "C" void kernel_launch(void* const* d_in, const int* in_sizes, int n_in,
                              void* d_out, int out_size, void* d_ws, size_t ws_size,
                              hipStream_t stream) {
    const float* X    = (const float*)d_in[0];
    const float* A    = (const float*)d_in[1];
    const float* W    = (const float*)d_in[2];
    const float* bias = (const float*)d_in[3];

    float* out0 = (float*)d_out;                         // [B,N,O]
    float* outA = out0 + (size_t)BB * NN * OO;           // [B,N,N]

    float*  dInv = (float*)d_ws;                         // 64 KB
    float*  Yf   = dInv + (size_t)BB * NN;               // 4 MB
    ushort* Ytb  = (ushort*)(Yf + (size_t)BB * NN * OO); // 2 MB

    k_rowsum<<<BB * NN, 256, 0, stream>>>(A, dInv);
    k_xw    <<<BB * NN / 16, 256, 0, stream>>>(X, W, dInv, Yf, Ytb);
    k_main  <<<BB * 128, 256, 0, stream>>>(A, Ytb, Yf, dInv, bias, out0, outA);
}